// Round 12
// baseline (1348.243 us; speedup 1.0000x reference)
//
#include <hip/hip_runtime.h>
#include <hip/hip_bf16.h>

// R12: direct register-cap control. Four rounds of gate vetoes traced to two
// broken instruments: (a) __launch_bounds__ 2nd arg -> cap mapping is
// uncalibratable folklore (R7 violated the fitted law); (b) numRegs is
// cap-filling, not demand (R10), so numRegs gates are meaningless.
// Fix: __attribute__((amdgpu_waves_per_eu(4))) pins cap = 512/4 = 128 VGPR
// DIRECTLY on a 256-thread kernel -> 4-wave blocks at the proven-no-spill
// cap-128 environment -> 4 blocks/CU (16 waves/CU, R7-proven co-residency).
// The 8-way kernel's phase body is fully INLINED so localSizeBytes is a TRUE
// spill detector (R6's veto was the noinline ABI frame). Gate:
// localSize==0 && occ>=4 -> launch 8-way (1024 x 256); else the proven
// (512,1) NPART=2 shape (937us, R11). Single launch, no error-ladder (R8).
#define NBAT 128
#define SS   48
#define DD   8
#define HDIM 8
#define NL   8
#define NC   7
#define PIX  (SS*SS)
#define RGN  (PIX*DD)            // one region: 18432 floats
#define GBAT (2*RGN)             // row+col regions per batch
#define BUFSZ ((size_t)NBAT*GBAT)      // one parity buffer (floats)
#define KVV  384
#define KVW  768
#define FLAGS_OFF ((size_t)2*BUFSZ)    // float offset of flags in d_ws
#define SMEM8 ((unsigned)((4*KVW + 264 + 784 + 8)*4))   // 16,512 B (256 thr)
#define SMEM2 ((unsigned)((8*KVW + 264 + 784 + 8)*4))   // 28,800 B (512 thr)

__device__ __forceinline__ float ldsel(const void* p, long i, bool bf) {
    return bf ? __bfloat162float(((const __hip_bfloat16*)p)[i])
              : ((const float*)p)[i];
}

__device__ __forceinline__ void flag_post(unsigned* f, unsigned v) {
    __threadfence();                                   // release: drain + L2 wb
    __hip_atomic_store(f, v, __ATOMIC_RELAXED, __HIP_MEMORY_SCOPE_AGENT);
}
__device__ __forceinline__ void flag_wait(unsigned* f, unsigned v) {
    while (__hip_atomic_load(f, __ATOMIC_RELAXED, __HIP_MEMORY_SCOPE_AGENT) < v)
        __builtin_amdgcn_s_sleep(1);
}

// Fast dt[48] attention phase core (R6 body, bitwise-stable since R4).
// own = this orientation's region (self-written, coalesced (prob*SS+tl));
// oth = opposite region ((tl*SS+prob), scattered). FIRST=1: layer 0, h0 as-is.
template <int NPROB, int NWAVT, int FIRST>
__device__ __forceinline__
void attn_core(const float4* __restrict__ gown, const float4* __restrict__ goth,
               float4* __restrict__ gout, float* __restrict__ kvw,
               const float* __restrict__ wb, int pbase, int wav, int lane, int tl)
{
    const float4* kv4 = reinterpret_cast<const float4*>(kvw);
    #pragma unroll 1
    for (int p = 0; p < NPROB/NWAVT; ++p) {
        const int prob = pbase + wav + p*NWAVT;
        const int aown = (prob*SS + tl)*2;

        float ht[DD];
        {
            const float4 o0 = gown[aown], o1 = gown[aown+1];
            if (FIRST) {
                ht[0]=o0.x; ht[1]=o0.y; ht[2]=o0.z; ht[3]=o0.w;
                ht[4]=o1.x; ht[5]=o1.y; ht[6]=o1.z; ht[7]=o1.w;
            } else {
                const int aoth = (tl*SS + prob)*2;
                const float4 t0 = goth[aoth], t1 = goth[aoth+1];
                ht[0]=fmaxf(0.f,o0.x+t0.x); ht[1]=fmaxf(0.f,o0.y+t0.y);
                ht[2]=fmaxf(0.f,o0.z+t0.z); ht[3]=fmaxf(0.f,o0.w+t0.w);
                ht[4]=fmaxf(0.f,o1.x+t1.x); ht[5]=fmaxf(0.f,o1.y+t1.y);
                ht[6]=fmaxf(0.f,o1.z+t1.z); ht[7]=fmaxf(0.f,o1.w+t1.w);
            }
        }

        // q/k/v projections; fold 0.5 (E^-0.5) * log2(e) into q for exp2.
        float q[HDIM];
        {
            float kk[HDIM], vv[HDIM];
            #pragma unroll
            for (int o = 0; o < HDIM; ++o) {
                float aq = 0.f, ak = 0.f, av = 0.f;
                #pragma unroll
                for (int d = 0; d < DD; ++d) {
                    aq += ht[d] * wb[o*8 + d];
                    ak += ht[d] * wb[64 + o*8 + d];
                    av += ht[d] * wb[128 + o*8 + d];
                }
                q[o] = aq * 0.72134752044f;  // 0.5 * log2(e)
                kk[o] = ak; vv[o] = av;
            }
            if (lane < SS) {   // lanes 48-63 would duplicate token 47: skip
                float4* kp = reinterpret_cast<float4*>(kvw + tl*8);
                kp[0] = make_float4(kk[0], kk[1], kk[2], kk[3]);
                kp[1] = make_float4(kk[4], kk[5], kk[6], kk[7]);
                float4* vp = reinterpret_cast<float4*>(kvw + KVV + tl*8);
                vp[0] = make_float4(vv[0], vv[1], vv[2], vv[3]);
                vp[1] = make_float4(vv[4], vv[5], vv[6], vv[7]);
            }
        }

        float ov[HDIM];
        #pragma unroll
        for (int hh = 0; hh < 2; ++hh) {
            float dt[SS];
            #pragma unroll
            for (int j2 = 0; j2 < SS; ++j2) {
                const float4 kk4 = kv4[j2*2 + hh];       // LDS same-addr broadcast
                float acc =  q[hh*4+0] * kk4.x;
                acc       += q[hh*4+1] * kk4.y;
                acc       += q[hh*4+2] * kk4.z;
                acc       += q[hh*4+3] * kk4.w;
                dt[j2] = acc;
            }
            // max tree (fmax exactly associative -> bitwise same as chain)
            float mt[24];
            #pragma unroll
            for (int t2 = 0; t2 < 24; ++t2) mt[t2] = fmaxf(dt[t2], dt[t2+24]);
            #pragma unroll
            for (int t2 = 0; t2 < 12; ++t2) mt[t2] = fmaxf(mt[t2], mt[t2+12]);
            #pragma unroll
            for (int t2 = 0; t2 < 6; ++t2)  mt[t2] = fmaxf(mt[t2], mt[t2+6]);
            #pragma unroll
            for (int t2 = 0; t2 < 3; ++t2)  mt[t2] = fmaxf(mt[t2], mt[t2+3]);
            const float m = fmaxf(fmaxf(mt[0], mt[1]), mt[2]);
            float s = 0.f;
            #pragma unroll
            for (int j2 = 0; j2 < SS; ++j2) {
                float pv = exp2f(dt[j2] - m);
                dt[j2] = pv; s += pv;
            }
            float o0 = 0.f, o1 = 0.f, o2 = 0.f, o3 = 0.f;
            #pragma unroll
            for (int j2 = 0; j2 < SS; ++j2) {
                const float4 vv4 = kv4[KVV/4 + j2*2 + hh];
                const float pv = dt[j2];
                o0 += pv * vv4.x;
                o1 += pv * vv4.y;
                o2 += pv * vv4.z;
                o3 += pv * vv4.w;
            }
            float rs = 1.f / s;
            ov[hh*4+0] = o0*rs; ov[hh*4+1] = o1*rs;
            ov[hh*4+2] = o2*rs; ov[hh*4+3] = o3*rs;
        }

        if (lane < SS) {
            float o8[DD];
            #pragma unroll
            for (int d = 0; d < DD; ++d) {
                float acc = wb[256 + d];
                #pragma unroll
                for (int o2 = 0; o2 < HDIM; ++o2) acc += ov[o2] * wb[192 + d*8 + o2];
                o8[d] = acc;
            }
            gout[aown]   = make_float4(o8[0], o8[1], o8[2], o8[3]);
            gout[aown+1] = make_float4(o8[4], o8[5], o8[6], o8[7]);
        }
    }
}

// noinline wrapper: preserves the PROVEN (512,1) fallback's codegen structure.
template <int NPROB, int NWAVT, int FIRST>
__device__ __attribute__((noinline))
void attn_phase_ni(const float4* __restrict__ gown, const float4* __restrict__ goth,
                   float4* __restrict__ gout, float* __restrict__ kvw,
                   const float* __restrict__ wb, int pbase, int wav, int lane, int tl)
{
    attn_core<NPROB,NWAVT,FIRST>(gown, goth, gout, kvw, wb, pbase, wav, lane, tl);
}

// ---------------------------------------------------------------------------
// 8-way kernel: 1024 blocks x 256 threads (2 axes x 4 quarters per batch).
// amdgpu_waves_per_eu(4) pins the VGPR cap at 512/4 = 128 (proven-no-spill
// environment); 4-wave blocks at 124-128 VGPR -> 4 blocks/CU. Body inlined
// so localSizeBytes is a true spill detector.
__global__ __launch_bounds__(256) __attribute__((amdgpu_waves_per_eu(4)))
void axial8(const void* xv, const void* enc_wv, const void* enc_bv,
            const void* pos_rowv, const void* pos_colv,
            const void* Wqv, const void* Wkv, const void* Wvv, const void* Wov,
            const void* bov, const void* cls_wv, const void* cls_bv,
            void* outv, void* wsv)
{
    constexpr int TB = 256, NWAVT = 4, NPROB = SS/4;

    const unsigned* xu = (const unsigned*)xv;
    int cnt = 0;
    #pragma unroll
    for (int t = 0; t < 32; ++t) {
        const unsigned w = xu[t];
        const int e = (w >> 7) & 0xff;
        cnt += (e > 100 && e < 150) ? 1 : 0;
    }
    const bool isbf = (cnt >= 20);

    float*    G     = (float*)wsv;
    unsigned* flags = (unsigned*)(G + FLAGS_OFF);

    extern __shared__ float smem[];
    float* kv = smem;              // per-wave k/v scratch [4*KVW]
    float* wb = kv + NWAVT*KVW;    // layer weights (own axis) [264]
    float* eb = wb + 264;          // enc params [784]
    float* cb = eb + 784;          // classifier logits [8]

    const int bid   = blockIdx.x;
    const int batch = bid & (NBAT-1);
    const int part  = bid >> 7;                 // 0..7
    const int axis  = part >> 2;                // 0: row, 1: col
    const int pbase = (part & 3) * NPROB;
    const int tid   = threadIdx.x;
    const int lane  = tid & 63;
    const int wav   = tid >> 6;
    const int tl    = lane < SS ? lane : SS-1;
    float* kvw = kv + wav*KVW;

    float* b0 = G + (size_t)batch*GBAT;
    float* b1 = G + BUFSZ + (size_t)batch*GBAT;
    float4* row0 = (float4*)b0;  float4* col0 = (float4*)(b0 + RGN);
    float4* row1 = (float4*)b1;  float4* col1 = (float4*)(b1 + RGN);

    for (int f = tid; f < 784; f += TB) {
        float v;
        if (f < 8)        v = ldsel(enc_wv, f, isbf);
        else if (f < 16)  v = ldsel(enc_bv, f-8, isbf);
        else if (f < 400) v = ldsel(pos_rowv, f-16, isbf);
        else              v = ldsel(pos_colv, f-400, isbf);
        eb[f] = v;
    }
    __syncthreads();

    // encoder: each block writes ONLY the quarter it reads at layer 0, in its
    // own orientation (no cross-block h0 dependency; parity-0 regions are
    // fully rewritten by layer 7 before the classifier reads them).
    {
        float4* own0 = axis ? col0 : row0;
        for (int idx = tid; idx < NPROB*SS; idx += TB) {
            const int prob = pbase + idx/SS, tok = idx%SS;
            const int i = axis ? prob : tok, j = axis ? tok : prob;
            const float xv2 = ldsel(xv, (long)batch*PIX + i*SS + j, isbf);
            float hv[DD];
            #pragma unroll
            for (int d = 0; d < DD; ++d)
                hv[d] = fmaxf(0.f, xv2*eb[d] + eb[8+d]) + eb[16 + i*8 + d] + eb[400 + j*8 + d];
            own0[(prob*SS+tok)*2]   = make_float4(hv[0], hv[1], hv[2], hv[3]);
            own0[(prob*SS+tok)*2+1] = make_float4(hv[4], hv[5], hv[6], hv[7]);
        }
    }

    // Layer l: reads parity l&1, writes parity (l+1)&1. WV(l)=l+1 posted
    // after the phase. Gate l>0: ALL 4 opposite-axis parts' WV >= l (own
    // reads are quarter-local/self-written; double-buffer => WV implies
    // read-safety for the buffer being overwritten).
    #pragma unroll 1
    for (int l = 0; l < NL; ++l) {
        __syncthreads();
        if (tid == 0 && l > 0) {
            const int ob = axis ? 0 : 4;
            #pragma unroll
            for (int qq = 0; qq < 4; ++qq)
                flag_wait(&flags[batch + (ob+qq)*NBAT], (unsigned)l);
            __threadfence();                 // acquire
        }
        const int la = l*2 + axis;
        for (int f = tid; f < 264; f += TB) {
            float v;
            if (f < 64)       v = ldsel(Wqv, la*64 + f, isbf);
            else if (f < 128) v = ldsel(Wkv, la*64 + f-64, isbf);
            else if (f < 192) v = ldsel(Wvv, la*64 + f-128, isbf);
            else if (f < 256) v = ldsel(Wov, la*64 + f-192, isbf);
            else              v = ldsel(bov, la*8 + f-256, isbf);
            wb[f] = v;
        }
        __syncthreads();

        const int par = l & 1;
        float4* rin  = par ? row1 : row0;  float4* cin  = par ? col1 : col0;
        float4* rout = par ? row0 : row1;  float4* cout = par ? col0 : col1;
        const float4* own = axis ? (const float4*)cin : (const float4*)rin;
        const float4* oth = axis ? (const float4*)rin : (const float4*)cin;
        float4* gout = axis ? cout : rout;

        if (l == 0) attn_core<NPROB,NWAVT,1>(own, oth, gout, kvw, wb, pbase, wav, lane, tl);
        else        attn_core<NPROB,NWAVT,0>(own, oth, gout, kvw, wb, pbase, wav, lane, tl);
        __syncthreads();

        if (tid == 0) flag_post(&flags[bid], (unsigned)(l + 1));
    }

    if (part != 0) return;

    if (tid == 0) {
        #pragma unroll
        for (int qp = 1; qp < 8; ++qp)
            flag_wait(&flags[batch + qp*NBAT], (unsigned)NL);
        __threadfence();
    }
    if (tid < NC) cb[tid] = ldsel(cls_bv, tid, isbf);
    __syncthreads();

    float pacc[NC] = {0.f,0.f,0.f,0.f,0.f,0.f,0.f};
    const float* cwf = (const float*)cls_wv;
    const __hip_bfloat16* cwb = (const __hip_bfloat16*)cls_wv;
    for (int p = tid; p < PIX; p += TB) {
        const int i = p / SS, j = p % SS;
        const float4 c0 = col0[p*2], c1 = col0[p*2+1];
        const float4 r0 = row0[(j*SS+i)*2], r1 = row0[(j*SS+i)*2+1];
        float mv =     fmaxf(0.f, c0.x + r0.x);
        mv = fmaxf(mv, fmaxf(0.f, c0.y + r0.y));
        mv = fmaxf(mv, fmaxf(0.f, c0.z + r0.z));
        mv = fmaxf(mv, fmaxf(0.f, c0.w + r0.w));
        mv = fmaxf(mv, fmaxf(0.f, c1.x + r1.x));
        mv = fmaxf(mv, fmaxf(0.f, c1.y + r1.y));
        mv = fmaxf(mv, fmaxf(0.f, c1.z + r1.z));
        mv = fmaxf(mv, fmaxf(0.f, c1.w + r1.w));
        if (isbf) {
            #pragma unroll
            for (int c = 0; c < NC; ++c) pacc[c] += mv * __bfloat162float(cwb[c*PIX + p]);
        } else {
            #pragma unroll
            for (int c = 0; c < NC; ++c) pacc[c] += mv * cwf[c*PIX + p];
        }
    }
    #pragma unroll
    for (int c = 0; c < NC; ++c) {
        #pragma unroll
        for (int off = 32; off > 0; off >>= 1) pacc[c] += __shfl_down(pacc[c], off, 64);
    }
    if (lane == 0) {
        #pragma unroll
        for (int c = 0; c < NC; ++c) atomicAdd(&cb[c], pacc[c]);
    }
    __syncthreads();

    if (tid < NC) {
        float m = cb[0];
        #pragma unroll
        for (int c = 1; c < NC; ++c) m = fmaxf(m, cb[c]);
        float s = 0.f;
        #pragma unroll
        for (int c = 0; c < NC; ++c) s += exp2f((cb[c]-m) * 1.44269504089f);
        const float e = exp2f((cb[tid]-m) * 1.44269504089f);
        const float r = e / s;
        if (isbf) ((__hip_bfloat16*)outv)[batch*NC + tid] = __float2bfloat16(r);
        else      ((float*)outv)[batch*NC + tid] = r;
    }
}

// ---------------------------------------------------------------------------
// Proven fallback: NPART=2, 256 blocks x 512 threads, (512,1), noinline body
// (R6/R11 shape, 937us).
__global__ void __launch_bounds__(512, 1)
axial2(const void* xv, const void* enc_wv, const void* enc_bv,
       const void* pos_rowv, const void* pos_colv,
       const void* Wqv, const void* Wkv, const void* Wvv, const void* Wov,
       const void* bov, const void* cls_wv, const void* cls_bv,
       void* outv, void* wsv)
{
    constexpr int TB = 512, NWAVT = 8, NPROB = SS;

    const unsigned* xu = (const unsigned*)xv;
    int cnt = 0;
    #pragma unroll
    for (int t = 0; t < 32; ++t) {
        const unsigned w = xu[t];
        const int e = (w >> 7) & 0xff;
        cnt += (e > 100 && e < 150) ? 1 : 0;
    }
    const bool isbf = (cnt >= 20);

    float*    G     = (float*)wsv;
    unsigned* flags = (unsigned*)(G + FLAGS_OFF);

    extern __shared__ float smem[];
    float* kv = smem;
    float* wb = kv + NWAVT*KVW;
    float* eb = wb + 264;
    float* cb = eb + 784;

    const int bid   = blockIdx.x;
    const int batch = bid & (NBAT-1);
    const int axis  = bid >> 7;
    const int tid   = threadIdx.x;
    const int lane  = tid & 63;
    const int wav   = tid >> 6;
    const int tl    = lane < SS ? lane : SS-1;
    float* kvw = kv + wav*KVW;

    float* b0 = G + (size_t)batch*GBAT;
    float* b1 = G + BUFSZ + (size_t)batch*GBAT;
    float4* row0 = (float4*)b0;  float4* col0 = (float4*)(b0 + RGN);
    float4* row1 = (float4*)b1;  float4* col1 = (float4*)(b1 + RGN);

    for (int f = tid; f < 784; f += TB) {
        float v;
        if (f < 8)        v = ldsel(enc_wv, f, isbf);
        else if (f < 16)  v = ldsel(enc_bv, f-8, isbf);
        else if (f < 400) v = ldsel(pos_rowv, f-16, isbf);
        else              v = ldsel(pos_colv, f-400, isbf);
        eb[f] = v;
    }
    __syncthreads();

    for (int p = tid; p < PIX; p += TB) {
        const int i = p / SS, j = p % SS;
        const float xv2 = ldsel(xv, (long)batch*PIX + p, isbf);
        float hv[DD];
        #pragma unroll
        for (int d = 0; d < DD; ++d)
            hv[d] = fmaxf(0.f, xv2*eb[d] + eb[8+d]) + eb[16 + i*8 + d] + eb[400 + j*8 + d];
        const float4 a = make_float4(hv[0], hv[1], hv[2], hv[3]);
        const float4 b = make_float4(hv[4], hv[5], hv[6], hv[7]);
        col0[p*2] = a;              col0[p*2+1] = b;
        row0[(j*SS+i)*2] = a;       row0[(j*SS+i)*2+1] = b;
    }

    #pragma unroll 1
    for (int l = 0; l < NL; ++l) {
        __syncthreads();
        if (tid == 0 && l > 0) {
            flag_wait(&flags[batch + (1-axis)*NBAT], (unsigned)l);
            __threadfence();
        }
        const int la = l*2 + axis;
        for (int f = tid; f < 264; f += TB) {
            float v;
            if (f < 64)       v = ldsel(Wqv, la*64 + f, isbf);
            else if (f < 128) v = ldsel(Wkv, la*64 + f-64, isbf);
            else if (f < 192) v = ldsel(Wvv, la*64 + f-128, isbf);
            else if (f < 256) v = ldsel(Wov, la*64 + f-192, isbf);
            else              v = ldsel(bov, la*8 + f-256, isbf);
            wb[f] = v;
        }
        __syncthreads();

        const int par = l & 1;
        float4* rin  = par ? row1 : row0;  float4* cin  = par ? col1 : col0;
        float4* rout = par ? row0 : row1;  float4* cout = par ? col0 : col1;
        const float4* own = axis ? (const float4*)cin : (const float4*)rin;
        const float4* oth = axis ? (const float4*)rin : (const float4*)cin;
        float4* gout = axis ? cout : rout;

        if (l == 0) attn_phase_ni<NPROB,NWAVT,1>(own, oth, gout, kvw, wb, 0, wav, lane, tl);
        else        attn_phase_ni<NPROB,NWAVT,0>(own, oth, gout, kvw, wb, 0, wav, lane, tl);
        __syncthreads();

        if (tid == 0) flag_post(&flags[bid], (unsigned)(l + 1));
    }

    if (axis != 0) return;

    if (tid == 0) {
        flag_wait(&flags[batch + NBAT], (unsigned)NL);
        __threadfence();
    }
    if (tid < NC) cb[tid] = ldsel(cls_bv, tid, isbf);
    __syncthreads();

    float pacc[NC] = {0.f,0.f,0.f,0.f,0.f,0.f,0.f};
    const float* cwf = (const float*)cls_wv;
    const __hip_bfloat16* cwb = (const __hip_bfloat16*)cls_wv;
    for (int p = tid; p < PIX; p += TB) {
        const int i = p / SS, j = p % SS;
        const float4 c0 = col0[p*2], c1 = col0[p*2+1];
        const float4 r0 = row0[(j*SS+i)*2], r1 = row0[(j*SS+i)*2+1];
        float mv =     fmaxf(0.f, c0.x + r0.x);
        mv = fmaxf(mv, fmaxf(0.f, c0.y + r0.y));
        mv = fmaxf(mv, fmaxf(0.f, c0.z + r0.z));
        mv = fmaxf(mv, fmaxf(0.f, c0.w + r0.w));
        mv = fmaxf(mv, fmaxf(0.f, c1.x + r1.x));
        mv = fmaxf(mv, fmaxf(0.f, c1.y + r1.y));
        mv = fmaxf(mv, fmaxf(0.f, c1.z + r1.z));
        mv = fmaxf(mv, fmaxf(0.f, c1.w + r1.w));
        if (isbf) {
            #pragma unroll
            for (int c = 0; c < NC; ++c) pacc[c] += mv * __bfloat162float(cwb[c*PIX + p]);
        } else {
            #pragma unroll
            for (int c = 0; c < NC; ++c) pacc[c] += mv * cwf[c*PIX + p];
        }
    }
    #pragma unroll
    for (int c = 0; c < NC; ++c) {
        #pragma unroll
        for (int off = 32; off > 0; off >>= 1) pacc[c] += __shfl_down(pacc[c], off, 64);
    }
    if (lane == 0) {
        #pragma unroll
        for (int c = 0; c < NC; ++c) atomicAdd(&cb[c], pacc[c]);
    }
    __syncthreads();

    if (tid < NC) {
        float m = cb[0];
        #pragma unroll
        for (int c = 1; c < NC; ++c) m = fmaxf(m, cb[c]);
        float s = 0.f;
        #pragma unroll
        for (int c = 0; c < NC; ++c) s += exp2f((cb[c]-m) * 1.44269504089f);
        const float e = exp2f((cb[tid]-m) * 1.44269504089f);
        const float r = e / s;
        if (isbf) ((__hip_bfloat16*)outv)[batch*NC + tid] = __float2bfloat16(r);
        else      ((float*)outv)[batch*NC + tid] = r;
    }
}

extern "C" void kernel_launch(void* const* d_in, const int* in_sizes, int n_in,
                              void* d_out, int out_size, void* d_ws, size_t ws_size,
                              hipStream_t stream) {
    (void)in_sizes; (void)n_in; (void)ws_size; (void)out_size;
    hipFuncSetAttribute(reinterpret_cast<const void*>(&axial8),
                        hipFuncAttributeMaxDynamicSharedMemorySize, SMEM8);
    hipFuncSetAttribute(reinterpret_cast<const void*>(&axial2),
                        hipFuncAttributeMaxDynamicSharedMemorySize, SMEM2);

    // zero epoch flags (stream-ordered, graph-capture-safe)
    hipMemsetAsync((char*)d_ws + FLAGS_OFF*4, 0, 1024*sizeof(unsigned), stream);

    void* ins[12];
    for (int i = 0; i < 12; ++i) ins[i] = d_in[i];
    void* args[14];
    for (int i = 0; i < 12; ++i) args[i] = &ins[i];
    args[12] = &d_out;
    args[13] = &d_ws;     // needs 2*BUFSZ*4 + 4KB ~= 37.75 MB (present since R5)

    // Deterministic gate, single launch (no error-ladder: R8 lesson).
    // With the body fully inlined, localSizeBytes==0 is a TRUE no-spill proof;
    // occ>=4 is the driver's own co-residency arithmetic for 1024 blocks.
    hipFuncAttributes fa{};
    const hipError_t qe = hipFuncGetAttributes(&fa, reinterpret_cast<const void*>(&axial8));
    int occ = 0;
    hipOccupancyMaxActiveBlocksPerMultiprocessor(
        &occ, reinterpret_cast<const void*>(&axial8), 256, SMEM8);

    if (qe == hipSuccess && fa.localSizeBytes == 0 && occ >= 4) {
        hipLaunchCooperativeKernel(reinterpret_cast<const void*>(&axial8),
                                   dim3(8*NBAT), dim3(256), args, SMEM8, stream);
    } else {
        hipLaunchCooperativeKernel(reinterpret_cast<const void*>(&axial2),
                                   dim3(2*NBAT), dim3(512), args, SMEM2, stream);
    }
}

// Round 13
// 1003.493 us; speedup vs baseline: 1.3436x; 1.3436x over previous
//
#include <hip/hip_runtime.h>
#include <hip/hip_bf16.h>

// R13: one kernel, one launch (R12 lesson: a co-compiled twin perturbed the
// proven fallback's regalloc into spilling -- FETCH 384MB->1.2GB at identical
// source). Experiment vs the 937us R11 shape (256 blocks x 512 thr, (512,1),
// NPART=2, flag-synced double-buffered global exchange): the block's
// OWN-orientation state never leaves the chip. hb[i][d][j] (RS=385, both
// access orientations conflict-free -- R4-proven) holds our phase output in
// LDS; only the OPPOSITE-axis tensor goes through global. relu(own+oth)
// fuses into the phase input read (no update passes, no extra barriers);
// the in-place hb overwrite is hazard-free: each column(row) is read-then-
// written by exactly its owning wave, layer boundary covered by the existing
// post-phase barrier. Encoder's global h0 stores deleted (hb only).
// Numerics: same values, same op order -> bitwise identical (absmax 0).
#define BDIM 512
#define NBLK 256
#define NBAT 128
#define SS   48
#define DD   8
#define HDIM 8
#define NL   8
#define NC   7
#define NWAV 8
#define PPW  6                   // problems per wave
#define PIX  (SS*SS)
#define RGN  (PIX*DD)            // one exchange region: 18432 floats
#define GBAT (2*RGN)             // row+col regions per batch
#define BUFSZ ((size_t)NBAT*GBAT)      // one parity buffer (floats)
#define KVV  384
#define KVW  768
#define KVTOT (NWAV*KVW)
#define RS   385                 // odd => conflict-free both orientations
#define HSZ  (SS*RS)             // 18480 floats
#define SMEM_FLOATS (HSZ + KVTOT + 264 + 784 + 8)
#define SMEM_BYTES  ((unsigned)(SMEM_FLOATS*4))   // 102,720 B -> 1 block/CU
#define FLAGS_OFF ((size_t)2*BUFSZ)    // float offset of flags in d_ws

__device__ __forceinline__ float ldsel(const void* p, long i, bool bf) {
    return bf ? __bfloat162float(((const __hip_bfloat16*)p)[i])
              : ((const float*)p)[i];
}

__device__ __forceinline__ void flag_post(unsigned* f, unsigned v) {
    __threadfence();                                   // release: drain + L2 wb
    __hip_atomic_store(f, v, __ATOMIC_RELAXED, __HIP_MEMORY_SCOPE_AGENT);
}
__device__ __forceinline__ void flag_wait(unsigned* f, unsigned v) {
    while (__hip_atomic_load(f, __ATOMIC_RELAXED, __HIP_MEMORY_SCOPE_AGENT) < v)
        __builtin_amdgcn_s_sleep(1);
}

// One axial-attention phase. Own state in hb (LDS, [i][d][j]); opposite-axis
// contribution from goth (global, (tl*SS+prob)*2, scattered, L2-absorbed).
// Output: hb in place (own, next layer) + gout (global, (prob*SS+tl)*2,
// coalesced, for the sibling). FIRST=1: layer 0, ht = h0 from hb directly.
// COLPHASE=0: problems are columns (row attention); 1: rows (col attention).
template <int COLPHASE, int FIRST>
__device__ __attribute__((noinline))
void attn_phase(float* __restrict__ hb, const float4* __restrict__ goth,
                float4* __restrict__ gout, float* __restrict__ kvw,
                const float* __restrict__ wb, int wav, int lane, int tl)
{
    const float4* kv4 = reinterpret_cast<const float4*>(kvw);
    #pragma unroll 1
    for (int p = 0; p < PPW; ++p) {
        const int prob = wav + p*NWAV;
        const int base = COLPHASE ? (prob*RS + tl) : (tl*RS + prob);

        float ht[DD];
        if (FIRST) {
            #pragma unroll
            for (int d = 0; d < DD; ++d) ht[d] = hb[base + d*SS];
        } else {
            const int aoth = (tl*SS + prob)*2;
            const float4 t0 = goth[aoth], t1 = goth[aoth+1];
            ht[0] = fmaxf(0.f, hb[base       ] + t0.x);
            ht[1] = fmaxf(0.f, hb[base +   SS] + t0.y);
            ht[2] = fmaxf(0.f, hb[base + 2*SS] + t0.z);
            ht[3] = fmaxf(0.f, hb[base + 3*SS] + t0.w);
            ht[4] = fmaxf(0.f, hb[base + 4*SS] + t1.x);
            ht[5] = fmaxf(0.f, hb[base + 5*SS] + t1.y);
            ht[6] = fmaxf(0.f, hb[base + 6*SS] + t1.z);
            ht[7] = fmaxf(0.f, hb[base + 7*SS] + t1.w);
        }

        // q/k/v projections; fold 0.5 (E^-0.5) * log2(e) into q for exp2.
        float q[HDIM];
        {
            float kk[HDIM], vv[HDIM];
            #pragma unroll
            for (int o = 0; o < HDIM; ++o) {
                float aq = 0.f, ak = 0.f, av = 0.f;
                #pragma unroll
                for (int d = 0; d < DD; ++d) {
                    aq += ht[d] * wb[o*8 + d];
                    ak += ht[d] * wb[64 + o*8 + d];
                    av += ht[d] * wb[128 + o*8 + d];
                }
                q[o] = aq * 0.72134752044f;  // 0.5 * log2(e)
                kk[o] = ak; vv[o] = av;
            }
            if (lane < SS) {   // lanes 48-63 would duplicate token 47: skip
                float4* kp = reinterpret_cast<float4*>(kvw + tl*8);
                kp[0] = make_float4(kk[0], kk[1], kk[2], kk[3]);
                kp[1] = make_float4(kk[4], kk[5], kk[6], kk[7]);
                float4* vp = reinterpret_cast<float4*>(kvw + KVV + tl*8);
                vp[0] = make_float4(vv[0], vv[1], vv[2], vv[3]);
                vp[1] = make_float4(vv[4], vv[5], vv[6], vv[7]);
            }
        }

        float ov[HDIM];
        #pragma unroll
        for (int hh = 0; hh < 2; ++hh) {
            float dt[SS];
            #pragma unroll
            for (int j2 = 0; j2 < SS; ++j2) {
                const float4 kk4 = kv4[j2*2 + hh];       // LDS same-addr broadcast
                float acc =  q[hh*4+0] * kk4.x;
                acc       += q[hh*4+1] * kk4.y;
                acc       += q[hh*4+2] * kk4.z;
                acc       += q[hh*4+3] * kk4.w;
                dt[j2] = acc;
            }
            // max tree (fmax exactly associative -> bitwise same as chain)
            float mt[24];
            #pragma unroll
            for (int t2 = 0; t2 < 24; ++t2) mt[t2] = fmaxf(dt[t2], dt[t2+24]);
            #pragma unroll
            for (int t2 = 0; t2 < 12; ++t2) mt[t2] = fmaxf(mt[t2], mt[t2+12]);
            #pragma unroll
            for (int t2 = 0; t2 < 6; ++t2)  mt[t2] = fmaxf(mt[t2], mt[t2+6]);
            #pragma unroll
            for (int t2 = 0; t2 < 3; ++t2)  mt[t2] = fmaxf(mt[t2], mt[t2+3]);
            const float m = fmaxf(fmaxf(mt[0], mt[1]), mt[2]);
            float s = 0.f;
            #pragma unroll
            for (int j2 = 0; j2 < SS; ++j2) {
                float pv = exp2f(dt[j2] - m);
                dt[j2] = pv; s += pv;
            }
            float o0 = 0.f, o1 = 0.f, o2 = 0.f, o3 = 0.f;
            #pragma unroll
            for (int j2 = 0; j2 < SS; ++j2) {
                const float4 vv4 = kv4[KVV/4 + j2*2 + hh];
                const float pv = dt[j2];
                o0 += pv * vv4.x;
                o1 += pv * vv4.y;
                o2 += pv * vv4.z;
                o3 += pv * vv4.w;
            }
            float rs = 1.f / s;
            ov[hh*4+0] = o0*rs; ov[hh*4+1] = o1*rs;
            ov[hh*4+2] = o2*rs; ov[hh*4+3] = o3*rs;
        }

        if (lane < SS) {
            float o8[DD];
            #pragma unroll
            for (int d = 0; d < DD; ++d) {
                float acc = wb[256 + d];
                #pragma unroll
                for (int o2 = 0; o2 < HDIM; ++o2) acc += ov[o2] * wb[192 + d*8 + o2];
                o8[d] = acc;
            }
            float4* gp = gout + (size_t)(prob*SS + tl)*2;
            gp[0] = make_float4(o8[0], o8[1], o8[2], o8[3]);
            gp[1] = make_float4(o8[4], o8[5], o8[6], o8[7]);
            #pragma unroll
            for (int d = 0; d < DD; ++d) hb[base + d*SS] = o8[d];
            // In-place hb overwrite is safe: this column(row) is read only by
            // this wave this layer, reads precede writes; next layer gated by
            // the post-phase __syncthreads.
        }
    }
}

__global__ void __launch_bounds__(BDIM, 1)   // the one proven-no-spill shape
axial_u(const void* xv, const void* enc_wv, const void* enc_bv,
        const void* pos_rowv, const void* pos_colv,
        const void* Wqv, const void* Wkv, const void* Wvv, const void* Wov,
        const void* bov, const void* cls_wv, const void* cls_bv,
        void* outv, void* wsv)
{
    // dtype sniff on x (wave-uniform): low bits of each dword are a plausible
    // bf16 exponent iff data is bf16-packed; random mantissa bits if fp32.
    const unsigned* xu = (const unsigned*)xv;
    int cnt = 0;
    #pragma unroll
    for (int t = 0; t < 32; ++t) {
        const unsigned w = xu[t];
        const int e = (w >> 7) & 0xff;
        cnt += (e > 100 && e < 150) ? 1 : 0;
    }
    const bool isbf = (cnt >= 20);

    float*    G     = (float*)wsv;
    unsigned* flags = (unsigned*)(G + FLAGS_OFF);

    extern __shared__ float smem[];
    float* hb = smem;              // own-orientation image [HSZ]
    float* kv = hb + HSZ;          // per-wave k/v scratch [KVTOT]
    float* wb = kv + KVTOT;        // layer weights (own axis) [264]
    float* eb = wb + 264;          // enc params [784]
    float* cb = eb + 784;          // classifier logits [8]

    const int bid   = blockIdx.x;
    const int batch = bid & (NBAT-1);
    const int axis  = bid >> 7;            // 0: row attention, 1: col attention
    const int tid   = threadIdx.x;
    const int lane  = tid & 63;
    const int wav   = tid >> 6;
    const int tl    = lane < SS ? lane : SS-1;
    float* kvw = kv + wav*KVW;

    float* b0 = G + (size_t)batch*GBAT;                 // parity-0 buffer
    float* b1 = G + BUFSZ + (size_t)batch*GBAT;         // parity-1 buffer
    float4* row0 = (float4*)b0;  float4* col0 = (float4*)(b0 + RGN);
    float4* row1 = (float4*)b1;  float4* col1 = (float4*)(b1 + RGN);

    // stage encoder/pos params
    for (int f = tid; f < 784; f += BDIM) {
        float v;
        if (f < 8)        v = ldsel(enc_wv, f, isbf);
        else if (f < 16)  v = ldsel(enc_bv, f-8, isbf);
        else if (f < 400) v = ldsel(pos_rowv, f-16, isbf);
        else              v = ldsel(pos_colv, f-400, isbf);
        eb[f] = v;
    }
    __syncthreads();

    // encoder: h0 = relu(x*enc_w + enc_b) + pos_row[i] + pos_col[j],
    // written to LDS hb ONLY (no global h0 traffic).
    for (int p = tid; p < PIX; p += BDIM) {
        const int i = p / SS, j = p % SS;
        const float xv2 = ldsel(xv, (long)batch*PIX + p, isbf);
        #pragma unroll
        for (int d = 0; d < DD; ++d) {
            float hv = fmaxf(0.f, xv2*eb[d] + eb[8+d]) + eb[16 + i*8 + d] + eb[400 + j*8 + d];
            hb[i*RS + d*SS + j] = hv;
        }
    }

    // Layer l: oth read parity l&1, own write parity (l+1)&1 (global regions
    // double-buffered exactly as R6; own-input now comes from hb).
    // Gate before layer l>0: sibling's WV(l-1) (their parity-(l&1) region
    // complete; double-buffer makes WV imply read-safety for our overwrite).
    #pragma unroll 1
    for (int l = 0; l < NL; ++l) {
        __syncthreads();                     // hb/phase writes visible, wb free
        if (tid == 0 && l > 0) {
            flag_wait(&flags[batch + (1-axis)*NBAT], (unsigned)l);
            __threadfence();                 // acquire: invalidate stale caches
        }
        const int la = l*2 + axis;
        for (int f = tid; f < 264; f += BDIM) {
            float v;
            if (f < 64)       v = ldsel(Wqv, la*64 + f, isbf);
            else if (f < 128) v = ldsel(Wkv, la*64 + f-64, isbf);
            else if (f < 192) v = ldsel(Wvv, la*64 + f-128, isbf);
            else if (f < 256) v = ldsel(Wov, la*64 + f-192, isbf);
            else              v = ldsel(bov, la*8 + f-256, isbf);
            wb[f] = v;
        }
        __syncthreads();                     // gate released + wb visible

        const int par = l & 1;
        float4* rin  = par ? row1 : row0;  float4* cin  = par ? col1 : col0;
        float4* rout = par ? row0 : row1;  float4* cout = par ? col0 : col1;
        const float4* oth = axis ? (const float4*)rin : (const float4*)cin;
        float4* gout = axis ? cout : rout;

        if (l == 0) {
            if (axis == 0) attn_phase<0,1>(hb, oth, gout, kvw, wb, wav, lane, tl);
            else           attn_phase<1,1>(hb, oth, gout, kvw, wb, wav, lane, tl);
        } else {
            if (axis == 0) attn_phase<0,0>(hb, oth, gout, kvw, wb, wav, lane, tl);
            else           attn_phase<1,0>(hb, oth, gout, kvw, wb, wav, lane, tl);
        }
        __syncthreads();                     // drains global stores + hb writes

        if (tid == 0) flag_post(&flags[bid], (unsigned)(l + 1));
    }

    if (axis != 0) return;

    // classifier (axis-0 block): h = relu(hb_own + col_oth), col output of
    // layer 7 lives in parity 0 (l=7 wrote parity (7+1)&1 = 0).
    if (tid == 0) {
        flag_wait(&flags[batch + NBAT], (unsigned)NL);
        __threadfence();
    }
    if (tid < NC) cb[tid] = ldsel(cls_bv, tid, isbf);
    __syncthreads();

    float pacc[NC] = {0.f,0.f,0.f,0.f,0.f,0.f,0.f};
    const float* cwf = (const float*)cls_wv;
    const __hip_bfloat16* cwb = (const __hip_bfloat16*)cls_wv;
    for (int p = tid; p < PIX; p += BDIM) {
        const int i = p / SS, j = p % SS, base = i*RS + j;
        const float4 c0 = col0[p*2], c1 = col0[p*2+1];
        float mv =     fmaxf(0.f, hb[base       ] + c0.x);
        mv = fmaxf(mv, fmaxf(0.f, hb[base +   SS] + c0.y));
        mv = fmaxf(mv, fmaxf(0.f, hb[base + 2*SS] + c0.z));
        mv = fmaxf(mv, fmaxf(0.f, hb[base + 3*SS] + c0.w));
        mv = fmaxf(mv, fmaxf(0.f, hb[base + 4*SS] + c1.x));
        mv = fmaxf(mv, fmaxf(0.f, hb[base + 5*SS] + c1.y));
        mv = fmaxf(mv, fmaxf(0.f, hb[base + 6*SS] + c1.z));
        mv = fmaxf(mv, fmaxf(0.f, hb[base + 7*SS] + c1.w));
        if (isbf) {
            #pragma unroll
            for (int c = 0; c < NC; ++c) pacc[c] += mv * __bfloat162float(cwb[c*PIX + p]);
        } else {
            #pragma unroll
            for (int c = 0; c < NC; ++c) pacc[c] += mv * cwf[c*PIX + p];
        }
    }
    #pragma unroll
    for (int c = 0; c < NC; ++c) {
        #pragma unroll
        for (int off = 32; off > 0; off >>= 1) pacc[c] += __shfl_down(pacc[c], off, 64);
    }
    if (lane == 0) {
        #pragma unroll
        for (int c = 0; c < NC; ++c) atomicAdd(&cb[c], pacc[c]);
    }
    __syncthreads();

    if (tid < NC) {
        float m = cb[0];
        #pragma unroll
        for (int c = 1; c < NC; ++c) m = fmaxf(m, cb[c]);
        float s = 0.f;
        #pragma unroll
        for (int c = 0; c < NC; ++c) s += exp2f((cb[c]-m) * 1.44269504089f);
        const float e = exp2f((cb[tid]-m) * 1.44269504089f);
        const float r = e / s;
        if (isbf) ((__hip_bfloat16*)outv)[batch*NC + tid] = __float2bfloat16(r);
        else      ((float*)outv)[batch*NC + tid] = r;
    }
}

extern "C" void kernel_launch(void* const* d_in, const int* in_sizes, int n_in,
                              void* d_out, int out_size, void* d_ws, size_t ws_size,
                              hipStream_t stream) {
    (void)in_sizes; (void)n_in; (void)ws_size; (void)out_size;
    hipFuncSetAttribute(reinterpret_cast<const void*>(&axial_u),
                        hipFuncAttributeMaxDynamicSharedMemorySize, SMEM_BYTES);

    // zero epoch flags (stream-ordered, graph-capture-safe)
    hipMemsetAsync((char*)d_ws + FLAGS_OFF*4, 0, NBLK*sizeof(unsigned), stream);

    void* ins[12];
    for (int i = 0; i < 12; ++i) ins[i] = d_in[i];
    void* args[14];
    for (int i = 0; i < 12; ++i) args[i] = &ins[i];
    args[12] = &d_out;
    args[13] = &d_ws;     // needs 2*BUFSZ*4 + 1KB ~= 37.75 MB (present since R5)

    // Single unconditional cooperative launch of the proven 256-block shape.
    hipLaunchCooperativeKernel(reinterpret_cast<const void*>(&axial_u),
                               dim3(NBLK), dim3(BDIM), args, SMEM_BYTES, stream);
}

// Round 14
// 770.506 us; speedup vs baseline: 1.7498x; 1.3024x over previous
//
#include <hip/hip_runtime.h>
#include <hip/hip_bf16.h>

// R14: delete the co-residency requirement. R13's recount showed flag/sync
// overhead is ~5us/layer, NOT 70 -- the real wall is 2 waves/SIMD, and every
// cooperative-launch occupancy attempt died on uncalibratable gates (5
// vetoes, 2 spills, 1 capture-poisoning crash). The flag protocol is what
// welds occupancy to correctness (all 256+ blocks must co-reside). Replace
// it with KERNEL-BOUNDARY sync: 10 plain launches (enc, 8x phase, cls) under
// graph capture (~2-4us each). Phase kernel = the proven R11 layer body,
// both axes in one grid (row & col phases of layer l are independent: both
// read parity l&1, write parity ~l&1), 1024 blocks x 256 threads (4 waves,
// 3 problems/wave), runtime l (no template twins -- R12 regalloc lesson).
// Occupancy becomes a performance knob: if 4 blocks/CU fit -> 16 waves/CU;
// if not, the grid runs in passes -- no deadlock, no launch failure, no
// cooperative API, no flags, no fences, no memset.
#define NBAT 128
#define SS   48
#define DD   8
#define HDIM 8
#define NL   8
#define NC   7
#define PIX  (SS*SS)
#define RGN  (PIX*DD)            // one exchange region: 18432 floats
#define GBAT (2*RGN)             // row+col regions per batch
#define BUFSZ ((size_t)NBAT*GBAT)      // one parity buffer (floats)
#define KVV  384
#define KVW  768

__device__ __forceinline__ float ldsel(const void* p, long i, bool bf) {
    return bf ? __bfloat162float(((const __hip_bfloat16*)p)[i])
              : ((const float*)p)[i];
}

__device__ __forceinline__ bool sniff_bf(const void* xv) {
    const unsigned* xu = (const unsigned*)xv;
    int cnt = 0;
    #pragma unroll
    for (int t = 0; t < 32; ++t) {
        const unsigned w = xu[t];
        const int e = (w >> 7) & 0xff;
        cnt += (e > 100 && e < 150) ? 1 : 0;
    }
    return cnt >= 20;
}

// ---------------------------------------------------------------------------
// Encoder: h0 = relu(x*enc_w + enc_b) + pos_row[i] + pos_col[j], written to
// parity-0 in BOTH layouts. 128 blocks (one per batch) x 256 threads.
__global__ __launch_bounds__(256)
void axial_enc(const void* xv, const void* enc_wv, const void* enc_bv,
               const void* pos_rowv, const void* pos_colv, void* wsv)
{
    const bool isbf = sniff_bf(xv);
    float* G = (float*)wsv;
    __shared__ float eb[784];

    const int batch = blockIdx.x;
    const int tid   = threadIdx.x;

    float* b0 = G + (size_t)batch*GBAT;
    float4* row0 = (float4*)b0;  float4* col0 = (float4*)(b0 + RGN);

    for (int f = tid; f < 784; f += 256) {
        float v;
        if (f < 8)        v = ldsel(enc_wv, f, isbf);
        else if (f < 16)  v = ldsel(enc_bv, f-8, isbf);
        else if (f < 400) v = ldsel(pos_rowv, f-16, isbf);
        else              v = ldsel(pos_colv, f-400, isbf);
        eb[f] = v;
    }
    __syncthreads();

    for (int p = tid; p < PIX; p += 256) {
        const int i = p / SS, j = p % SS;
        const float xv2 = ldsel(xv, (long)batch*PIX + p, isbf);
        float hv[DD];
        #pragma unroll
        for (int d = 0; d < DD; ++d)
            hv[d] = fmaxf(0.f, xv2*eb[d] + eb[8+d]) + eb[16 + i*8 + d] + eb[400 + j*8 + d];
        const float4 a = make_float4(hv[0], hv[1], hv[2], hv[3]);
        const float4 b = make_float4(hv[4], hv[5], hv[6], hv[7]);
        col0[p*2] = a;              col0[p*2+1] = b;            // [i][j][d]
        row0[(j*SS+i)*2] = a;       row0[(j*SS+i)*2+1] = b;     // [j][i][d]
    }
}

// ---------------------------------------------------------------------------
// One layer, both axes: 1024 blocks x 256 threads. Block = (batch, part);
// part 0-3 = row-attention quarters, 4-7 = col-attention quarters.
// Reads parity l&1 (own coalesced (prob*SS+tl), oth scattered (tl*SS+prob)),
// writes own-layout region of parity ~l&1. relu(own+oth) fused at input
// (l>0); l==0 reads h0 as-is. Kernel boundary = global barrier (no flags).
__global__ __launch_bounds__(256)
void axial_phase(const void* xv, const void* Wqv, const void* Wkv,
                 const void* Wvv, const void* Wov, const void* bov,
                 void* wsv, int l)
{
    const bool isbf = sniff_bf(xv);
    float* G = (float*)wsv;

    __shared__ float kv[4*KVW];
    __shared__ float wb[264];

    const int bid   = blockIdx.x;
    const int batch = bid & (NBAT-1);
    const int part  = bid >> 7;                 // 0..7
    const int axis  = part >> 2;                // 0: row, 1: col
    const int pbase = (part & 3) * 12;          // quarter of 48 problems
    const int tid   = threadIdx.x;
    const int lane  = tid & 63;
    const int wav   = tid >> 6;                 // 0..3
    const int tl    = lane < SS ? lane : SS-1;
    float* kvw = kv + wav*KVW;
    const float4* kv4 = reinterpret_cast<const float4*>(kvw);

    float* b0 = G + (size_t)batch*GBAT;
    float* b1 = G + BUFSZ + (size_t)batch*GBAT;
    float4* row0 = (float4*)b0;  float4* col0 = (float4*)(b0 + RGN);
    float4* row1 = (float4*)b1;  float4* col1 = (float4*)(b1 + RGN);

    const int la = l*2 + axis;
    for (int f = tid; f < 264; f += 256) {
        float v;
        if (f < 64)       v = ldsel(Wqv, la*64 + f, isbf);
        else if (f < 128) v = ldsel(Wkv, la*64 + f-64, isbf);
        else if (f < 192) v = ldsel(Wvv, la*64 + f-128, isbf);
        else if (f < 256) v = ldsel(Wov, la*64 + f-192, isbf);
        else              v = ldsel(bov, la*8 + f-256, isbf);
        wb[f] = v;
    }
    __syncthreads();

    const int par = l & 1;
    float4* rin  = par ? row1 : row0;  float4* cin  = par ? col1 : col0;
    float4* rout = par ? row0 : row1;  float4* cout = par ? col0 : col1;
    const float4* own = axis ? (const float4*)cin : (const float4*)rin;
    const float4* oth = axis ? (const float4*)rin : (const float4*)cin;
    float4* gout = axis ? cout : rout;
    const bool first = (l == 0);

    #pragma unroll 1
    for (int p = 0; p < 3; ++p) {
        const int prob = pbase + wav + p*4;
        const int aown = (prob*SS + tl)*2;

        float ht[DD];
        {
            const float4 o0 = own[aown], o1 = own[aown+1];
            if (first) {
                ht[0]=o0.x; ht[1]=o0.y; ht[2]=o0.z; ht[3]=o0.w;
                ht[4]=o1.x; ht[5]=o1.y; ht[6]=o1.z; ht[7]=o1.w;
            } else {
                const int aoth = (tl*SS + prob)*2;
                const float4 t0 = oth[aoth], t1 = oth[aoth+1];
                ht[0]=fmaxf(0.f,o0.x+t0.x); ht[1]=fmaxf(0.f,o0.y+t0.y);
                ht[2]=fmaxf(0.f,o0.z+t0.z); ht[3]=fmaxf(0.f,o0.w+t0.w);
                ht[4]=fmaxf(0.f,o1.x+t1.x); ht[5]=fmaxf(0.f,o1.y+t1.y);
                ht[6]=fmaxf(0.f,o1.z+t1.z); ht[7]=fmaxf(0.f,o1.w+t1.w);
            }
        }

        // q/k/v projections; fold 0.5 (E^-0.5) * log2(e) into q for exp2.
        float q[HDIM];
        {
            float kk[HDIM], vv[HDIM];
            #pragma unroll
            for (int o = 0; o < HDIM; ++o) {
                float aq = 0.f, ak = 0.f, av = 0.f;
                #pragma unroll
                for (int d = 0; d < DD; ++d) {
                    aq += ht[d] * wb[o*8 + d];
                    ak += ht[d] * wb[64 + o*8 + d];
                    av += ht[d] * wb[128 + o*8 + d];
                }
                q[o] = aq * 0.72134752044f;  // 0.5 * log2(e)
                kk[o] = ak; vv[o] = av;
            }
            if (lane < SS) {   // lanes 48-63 would duplicate token 47: skip
                float4* kp = reinterpret_cast<float4*>(kvw + tl*8);
                kp[0] = make_float4(kk[0], kk[1], kk[2], kk[3]);
                kp[1] = make_float4(kk[4], kk[5], kk[6], kk[7]);
                float4* vp = reinterpret_cast<float4*>(kvw + KVV + tl*8);
                vp[0] = make_float4(vv[0], vv[1], vv[2], vv[3]);
                vp[1] = make_float4(vv[4], vv[5], vv[6], vv[7]);
            }
        }

        float ov[HDIM];
        #pragma unroll
        for (int hh = 0; hh < 2; ++hh) {
            float dt[SS];
            #pragma unroll
            for (int j2 = 0; j2 < SS; ++j2) {
                const float4 kk4 = kv4[j2*2 + hh];       // LDS same-addr broadcast
                float acc =  q[hh*4+0] * kk4.x;
                acc       += q[hh*4+1] * kk4.y;
                acc       += q[hh*4+2] * kk4.z;
                acc       += q[hh*4+3] * kk4.w;
                dt[j2] = acc;
            }
            // max tree (fmax exactly associative -> bitwise same as chain)
            float mt[24];
            #pragma unroll
            for (int t2 = 0; t2 < 24; ++t2) mt[t2] = fmaxf(dt[t2], dt[t2+24]);
            #pragma unroll
            for (int t2 = 0; t2 < 12; ++t2) mt[t2] = fmaxf(mt[t2], mt[t2+12]);
            #pragma unroll
            for (int t2 = 0; t2 < 6; ++t2)  mt[t2] = fmaxf(mt[t2], mt[t2+6]);
            #pragma unroll
            for (int t2 = 0; t2 < 3; ++t2)  mt[t2] = fmaxf(mt[t2], mt[t2+3]);
            const float m = fmaxf(fmaxf(mt[0], mt[1]), mt[2]);
            float s = 0.f;
            #pragma unroll
            for (int j2 = 0; j2 < SS; ++j2) {
                float pv = exp2f(dt[j2] - m);
                dt[j2] = pv; s += pv;
            }
            float o0 = 0.f, o1 = 0.f, o2 = 0.f, o3 = 0.f;
            #pragma unroll
            for (int j2 = 0; j2 < SS; ++j2) {
                const float4 vv4 = kv4[KVV/4 + j2*2 + hh];
                const float pv = dt[j2];
                o0 += pv * vv4.x;
                o1 += pv * vv4.y;
                o2 += pv * vv4.z;
                o3 += pv * vv4.w;
            }
            float rs = 1.f / s;
            ov[hh*4+0] = o0*rs; ov[hh*4+1] = o1*rs;
            ov[hh*4+2] = o2*rs; ov[hh*4+3] = o3*rs;
        }

        if (lane < SS) {
            float o8[DD];
            #pragma unroll
            for (int d = 0; d < DD; ++d) {
                float acc = wb[256 + d];
                #pragma unroll
                for (int o2 = 0; o2 < HDIM; ++o2) acc += ov[o2] * wb[192 + d*8 + o2];
                o8[d] = acc;
            }
            gout[aown]   = make_float4(o8[0], o8[1], o8[2], o8[3]);
            gout[aown+1] = make_float4(o8[4], o8[5], o8[6], o8[7]);
        }
    }
}

// ---------------------------------------------------------------------------
// Classifier: final h = relu(row+col) of parity 0 (layer 7 wrote parity 0);
// max over d, dot with cls_w, softmax. 128 blocks x 256 threads.
__global__ __launch_bounds__(256)
void axial_cls(const void* xv, const void* cls_wv, const void* cls_bv,
               void* outv, void* wsv)
{
    const bool isbf = sniff_bf(xv);
    float* G = (float*)wsv;
    __shared__ float cb[NC];

    const int batch = blockIdx.x;
    const int tid   = threadIdx.x;
    const int lane  = tid & 63;

    float* b0 = G + (size_t)batch*GBAT;
    float4* row0 = (float4*)b0;  float4* col0 = (float4*)(b0 + RGN);

    if (tid < NC) cb[tid] = ldsel(cls_bv, tid, isbf);
    __syncthreads();

    float pacc[NC] = {0.f,0.f,0.f,0.f,0.f,0.f,0.f};
    const float* cwf = (const float*)cls_wv;
    const __hip_bfloat16* cwb = (const __hip_bfloat16*)cls_wv;
    for (int p = tid; p < PIX; p += 256) {
        const int i = p / SS, j = p % SS;
        const float4 c0 = col0[p*2], c1 = col0[p*2+1];
        const float4 r0 = row0[(j*SS+i)*2], r1 = row0[(j*SS+i)*2+1];
        float mv =     fmaxf(0.f, c0.x + r0.x);
        mv = fmaxf(mv, fmaxf(0.f, c0.y + r0.y));
        mv = fmaxf(mv, fmaxf(0.f, c0.z + r0.z));
        mv = fmaxf(mv, fmaxf(0.f, c0.w + r0.w));
        mv = fmaxf(mv, fmaxf(0.f, c1.x + r1.x));
        mv = fmaxf(mv, fmaxf(0.f, c1.y + r1.y));
        mv = fmaxf(mv, fmaxf(0.f, c1.z + r1.z));
        mv = fmaxf(mv, fmaxf(0.f, c1.w + r1.w));
        if (isbf) {
            #pragma unroll
            for (int c = 0; c < NC; ++c) pacc[c] += mv * __bfloat162float(cwb[c*PIX + p]);
        } else {
            #pragma unroll
            for (int c = 0; c < NC; ++c) pacc[c] += mv * cwf[c*PIX + p];
        }
    }
    #pragma unroll
    for (int c = 0; c < NC; ++c) {
        #pragma unroll
        for (int off = 32; off > 0; off >>= 1) pacc[c] += __shfl_down(pacc[c], off, 64);
    }
    if (lane == 0) {
        #pragma unroll
        for (int c = 0; c < NC; ++c) atomicAdd(&cb[c], pacc[c]);
    }
    __syncthreads();

    if (tid < NC) {
        float m = cb[0];
        #pragma unroll
        for (int c = 1; c < NC; ++c) m = fmaxf(m, cb[c]);
        float s = 0.f;
        #pragma unroll
        for (int c = 0; c < NC; ++c) s += exp2f((cb[c]-m) * 1.44269504089f);
        const float e = exp2f((cb[tid]-m) * 1.44269504089f);
        const float r = e / s;
        if (isbf) ((__hip_bfloat16*)outv)[batch*NC + tid] = __float2bfloat16(r);
        else      ((float*)outv)[batch*NC + tid] = r;
    }
}

extern "C" void kernel_launch(void* const* d_in, const int* in_sizes, int n_in,
                              void* d_out, int out_size, void* d_ws, size_t ws_size,
                              hipStream_t stream) {
    (void)in_sizes; (void)n_in; (void)ws_size; (void)out_size;
    // d_ws: 2 parity buffers = 2*BUFSZ*4 ~= 37.75 MB (present since R5).
    // Kernel boundaries provide all inter-phase synchronization (stream order).
    axial_enc<<<dim3(NBAT), dim3(256), 0, stream>>>(
        d_in[0], d_in[1], d_in[2], d_in[3], d_in[4], d_ws);
    for (int l = 0; l < NL; ++l) {
        axial_phase<<<dim3(8*NBAT), dim3(256), 0, stream>>>(
            d_in[0], d_in[5], d_in[6], d_in[7], d_in[8], d_in[9], d_ws, l);
    }
    axial_cls<<<dim3(NBAT), dim3(256), 0, stream>>>(
        d_in[0], d_in[10], d_in[11], d_out, d_ws);
}